// Round 3
// baseline (466.669 us; speedup 1.0000x reference)
//
#include <hip/hip_runtime.h>

// SpatialPool: fm [B=16, C=512, H=38, W=38] f32, replication pad 1,
// out[b, (h*W+w)*9*C + k*C + c] = fm[b, c, clamp(h+k/3-1), clamp(w+k%3-1)]
//
// R2: float4 stores were neutral vs scalar (both ~190us) -> write-stream
// shape bound, not instruction bound.
// R3: XCD swizzle — all 4 channel-chunks of one (b,h) get the same
// blockIdx%8 (same XCD), so the per-XCD L2 assembles full 2KB output
// lines instead of 512B fragments interleaved across 4 non-coherent L2s.

#define BB 16
#define CC 512
#define HH 38
#define WW 38
#define HW (HH * WW)          // 1444
#define KK 9
#define CCH 128               // channel chunk per block
#define NCH (CC / CCH)        // 4
#define LC (CCH + 4)          // 132: rows 16B-aligned, bank step 4
#define NTHREADS 512
#define NBH (BB * HH)         // 608

__global__ __launch_bounds__(NTHREADS) void spatial_pool_kernel(
    const float* __restrict__ fm, float* __restrict__ out)
{
    __shared__ float lds[3][WW][LC];         // 60,192 B -> 2 blocks/CU

    // ---- XCD-aware decode: bh % 8 == blockIdx % 8 for all 4 chunks ----
    const int blk   = blockIdx.x;            // 0..2431
    const int x     = blk & 7;               // XCD slot
    const int g     = blk >> 3;              // 0..303
    const int chunk = g & (NCH - 1);         // 0..3 (varies every 8 blocks)
    const int bh    = (g >> 2) * 8 + x;      // 0..607, fixed mod 8 per group
    const int h     = bh % HH;
    const int b     = bh / HH;
    const int c0    = chunk * CCH;

    // clamped source rows for di = 0,1,2
    const int r0 = (h - 1 < 0) ? 0 : h - 1;
    const int r1 = h;
    const int r2 = (h + 1 > HH - 1) ? HH - 1 : h + 1;

    // ---- stage: 3 rows x CCH channels x WW into LDS (w-major) ----
    const float* base = fm + ((size_t)b * CC + c0) * HW;
    const int NL2 = 3 * CCH * (WW / 2);      // 7296 float2 loads
    for (int idx = threadIdx.x; idx < NL2; idx += NTHREADS) {
        int w2 = idx % (WW / 2);
        int rc = idx / (WW / 2);             // r*CCH + c
        int c  = rc & (CCH - 1);
        int r  = rc >> 7;
        int hr = (r == 0) ? r0 : ((r == 1) ? r1 : r2);
        const float2 v = *(const float2*)(base + c * HW + hr * WW + 2 * w2);
        lds[r][2 * w2 + 0][c] = v.x;
        lds[r][2 * w2 + 1][c] = v.y;
    }
    __syncthreads();

    // ---- store: float4 per lane; lanes 0..31 share (w,k), consecutive c ----
    float4* outb4 = (float4*)(out + (((size_t)b * HW + (size_t)h * WW) * KK) * CC + c0);
    const int NST4 = WW * KK * (CCH / 4);    // 10944
    for (int i = threadIdx.x; i < NST4; i += NTHREADS) {
        int c4 = i & 31;
        int wk = i >> 5;                     // w*KK + k
        int w  = wk / KK;
        int k  = wk - w * KK;
        int di = k / 3;
        int dj = k - di * 3;
        int wp = w + dj - 1;
        wp = (wp < 0) ? 0 : ((wp > WW - 1) ? WW - 1 : wp);
        const float4 v = *(const float4*)&lds[di][wp][c4 * 4];   // ds_read_b128
        outb4[(size_t)wk * (CC / 4) + c4] = v;                   // global_store_dwordx4
    }
}

extern "C" void kernel_launch(void* const* d_in, const int* in_sizes, int n_in,
                              void* d_out, int out_size, void* d_ws, size_t ws_size,
                              hipStream_t stream) {
    const float* fm = (const float*)d_in[0];
    float* out = (float*)d_out;
    dim3 grid(NBH * NCH);                    // 2432 blocks
    dim3 block(NTHREADS);
    spatial_pool_kernel<<<grid, block, 0, stream>>>(fm, out);
}